// Round 9
// baseline (173.868 us; speedup 1.0000x reference)
//
#include <hip/hip_runtime.h>

// GaussianDynamics recurrent cell as a parallel affine scan.
// x_t = S_t x_{t-1} + o_t,  S_t = I + (A - xic_t C) dt,  o_t = xic_t dy_t
// out_t = C x_{t-1} dt  (pre-update state)
//
// R9 vs R7 (98.8us): cut the per-wave overhead term instead of chasing
// overlap (R4/R8 pipelining both lost to occupancy/lockstep).
//  - SPT=8: 1000 = 125*8 exactly -> no per-step tail guard (one cndmask set
//    per thread). 2 waves per row instead of 4: wave-scan (108 inst) +
//    fixup + addressing paid half as many times per row.
//  - TPB=256 = 2 INDEPENDENT rows x 2 waves. Single __syncthreads for the
//    2-wave wsum exchange (waves 0/2 publish, 1/3 consume).
//  - Per-wave global_load_lds staging (8x16B) of its own 8KB LDS half,
//    XOR-involution (granule g ^ ((g>>3)&7)) applied to the GLOBAL source;
//    thread chunk = exactly one 8-granule swizzle group -> ds_read_b128
//    pattern uses all 32 banks at full throughput (R7's SPT=4 misalignment
//    left 1M conflict cycles).
//  - dy direct: 4 contiguous dwordx4/thread; outputs 4 NT float4/thread.

constexpr int BATCH = 16384;
constexpr int TLEN  = 1000;
constexpr int TPB   = 256;
constexpr int SPT   = 8;               // 125 active threads per row
constexpr int RPB   = 2;               // independent rows per block
constexpr int NBLK  = BATCH / RPB;     // 8192 blocks

typedef float vfloat4 __attribute__((ext_vector_type(4)));
typedef float vfloat2 __attribute__((ext_vector_type(2)));

template <int CTRL, int ROWMASK>
__device__ __forceinline__ float dppf(float oldv, float srcv) {
    return __int_as_float(__builtin_amdgcn_update_dpp(
        __float_as_int(oldv), __float_as_int(srcv), CTRL, ROWMASK, 0xf, false));
}

__global__ __launch_bounds__(TPB, 4) void gd_scan_kernel(
    const float* __restrict__ xicovs,  // [B,T,2,2]
    const float* __restrict__ dyv,     // [B,T,2]
    const float* __restrict__ cA,      // [2,2]
    const float* __restrict__ Cm,      // [2,2]
    const float* __restrict__ x0,      // [B,2]
    const float* __restrict__ dtp,     // [1]
    float* __restrict__ out)           // [B,T,2] then [B,2]
{
    __shared__ vfloat4 s_xc[RPB][1024];   // AoS granules, 16KB per row
    __shared__ float wsum[RPB][6];

    const int tid  = threadIdx.x;
    const int lane = tid & 63;
    const int rb   = tid >> 7;            // row within block (0/1)
    const int w01  = (tid >> 6) & 1;      // wave within row (0/1)
    const int r    = tid & 127;           // thread within row
    const int row  = blockIdx.x * RPB + rb;
    const bool valid = (r < 125);         // r*8 <= 992

    // ---- stage own 512-granule half: 8x global_load_lds(16B), pre-swizzled ----
    {
        const float* rowx = xicovs + (size_t)row * (TLEN * 4);
#pragma unroll
        for (int k = 0; k < 8; ++k) {
            const int p  = k * 64 + lane;              // position in half
            int g = 512 * w01 + (p ^ ((p >> 3) & 7));  // involution source granule
            if (g > TLEN - 1) g = TLEN - 1;
            __builtin_amdgcn_global_load_lds(
                (const __attribute__((address_space(1))) void*)(rowx + (size_t)g * 4),
                (__attribute__((address_space(3))) void*)&s_xc[rb][512 * w01 + k * 64],
                16, 0, 0);
        }
    }

    // ---- dy: 4 contiguous dwordx4 per thread (64B), clamped for tail ----
    const int rbase = valid ? r : 124;
    const vfloat4* gd4 = reinterpret_cast<const vfloat4*>(
        dyv + (size_t)row * (TLEN * 2) + (size_t)rbase * 16);
    const vfloat4 d0 = gd4[0], d1 = gd4[1], d2 = gd4[2], d3 = gd4[3];

    // ---- uniform params ----
    const float dts = dtp[0];
    const float Cd00 = Cm[0] * dts, Cd01 = Cm[1] * dts, Cd10 = Cm[2] * dts, Cd11 = Cm[3] * dts;
    const float nCd00 = -Cd00, nCd01 = -Cd01, nCd10 = -Cd10, nCd11 = -Cd11;
    const float Ad00 = 1.f + cA[0] * dts, Ad01 = cA[1] * dts;
    const float Ad10 = cA[2] * dts,       Ad11 = 1.f + cA[3] * dts;
    const float xa = x0[2 * row], xb = x0[2 * row + 1];

    // ---- drain this wave's LDS-DMA (+ dy) ----
    asm volatile("s_waitcnt vmcnt(0)" ::: "memory");

    // ---- read own 8 timesteps: swizzled ds_read_b128, full-throughput ----
    vfloat4 xc[SPT];
#pragma unroll
    for (int s = 0; s < SPT; ++s) {
        const int pos = 8 * r + (s ^ (r & 7));  // = (8r+s) ^ (((8r+s)>>3)&7)
        xc[s] = s_xc[rb][pos];
    }
    const float dy0s[SPT] = {d0.x, d0.z, d1.x, d1.z, d2.x, d2.z, d3.x, d3.z};
    const float dy1s[SPT] = {d0.y, d0.w, d1.y, d1.w, d2.y, d2.w, d3.y, d3.w};

    // ---- per-step affine (S,o): S = Ad + xi*nCd, o = xi*dy; compose ----
    float S00s[SPT], S01s[SPT], S10s[SPT], S11s[SPT], o0s[SPT], o1s[SPT];
    float M00 = 1.f, M01 = 0.f, M10 = 0.f, M11 = 1.f, c0 = 0.f, c1 = 0.f;
#pragma unroll
    for (int s = 0; s < SPT; ++s) {
        const float xi00 = xc[s].x, xi01 = xc[s].y, xi10 = xc[s].z, xi11 = xc[s].w;
        const float S00 = Ad00 + xi00 * nCd00 + xi01 * nCd10;
        const float S01 = Ad01 + xi00 * nCd01 + xi01 * nCd11;
        const float S10 = Ad10 + xi10 * nCd00 + xi11 * nCd10;
        const float S11 = Ad11 + xi10 * nCd01 + xi11 * nCd11;
        const float o0 = xi00 * dy0s[s] + xi01 * dy1s[s];
        const float o1 = xi10 * dy0s[s] + xi11 * dy1s[s];
        S00s[s] = S00; S01s[s] = S01; S10s[s] = S10; S11s[s] = S11; o0s[s] = o0; o1s[s] = o1;
        const float n00 = S00 * M00 + S01 * M10;
        const float n01 = S00 * M01 + S01 * M11;
        const float n10 = S10 * M00 + S11 * M10;
        const float n11 = S10 * M01 + S11 * M11;
        const float nc0 = S00 * c0 + S01 * c1 + o0;
        const float nc1 = S10 * c0 + S11 * c1 + o1;
        M00 = n00; M01 = n01; M10 = n10; M11 = n11; c0 = nc0; c1 = nc1;
    }
    // tail threads (r>=125) contribute identity to the scan (one-time select)
    if (!valid) { M00 = 1.f; M01 = 0.f; M10 = 0.f; M11 = 1.f; c0 = 0.f; c1 = 0.f; }

    // ---- wave-level inclusive scan via DPP (VALU, no LDS pipe) ----
#define SCAN_STEP(CTRL, RM)                                        \
    do {                                                           \
        const float m00 = dppf<CTRL, RM>(1.f, M00);                \
        const float m01 = dppf<CTRL, RM>(0.f, M01);                \
        const float m10 = dppf<CTRL, RM>(0.f, M10);                \
        const float m11 = dppf<CTRL, RM>(1.f, M11);                \
        const float lc0 = dppf<CTRL, RM>(0.f, c0);                 \
        const float lc1 = dppf<CTRL, RM>(0.f, c1);                 \
        const float n00 = M00 * m00 + M01 * m10;                   \
        const float n01 = M00 * m01 + M01 * m11;                   \
        const float n10 = M10 * m00 + M11 * m10;                   \
        const float n11 = M10 * m01 + M11 * m11;                   \
        const float nc0 = M00 * lc0 + M01 * lc1 + c0;              \
        const float nc1 = M10 * lc0 + M11 * lc1 + c1;              \
        M00 = n00; M01 = n01; M10 = n10; M11 = n11;                \
        c0 = nc0; c1 = nc1;                                        \
    } while (0)

    SCAN_STEP(0x111, 0xf);  // row_shr:1
    SCAN_STEP(0x112, 0xf);  // row_shr:2
    SCAN_STEP(0x114, 0xf);  // row_shr:4
    SCAN_STEP(0x118, 0xf);  // row_shr:8
    SCAN_STEP(0x142, 0xa);  // row_bcast:15 -> rows 1,3
    SCAN_STEP(0x143, 0xc);  // row_bcast:31 -> rows 2,3
#undef SCAN_STEP

    // ---- 2-wave fixup: waves 0/2 publish totals, waves 1/3 consume ----
    if (w01 == 0 && lane == 63) {
        wsum[rb][0] = M00; wsum[rb][1] = M01; wsum[rb][2] = M10; wsum[rb][3] = M11;
        wsum[rb][4] = c0;  wsum[rb][5] = c1;
    }
    __syncthreads();

    float P00 = 1.f, P01 = 0.f, P10 = 0.f, P11 = 1.f, Pc0 = 0.f, Pc1 = 0.f;
    if (w01) {
        P00 = wsum[rb][0]; P01 = wsum[rb][1]; P10 = wsum[rb][2]; P11 = wsum[rb][3];
        Pc0 = wsum[rb][4]; Pc1 = wsum[rb][5];
    }

    // ---- within-wave exclusive = inclusive of lane-1 ----
    float e00 = __shfl_up(M00, 1), e01 = __shfl_up(M01, 1);
    float e10 = __shfl_up(M10, 1), e11 = __shfl_up(M11, 1);
    float ec0 = __shfl_up(c0, 1),  ec1 = __shfl_up(c1, 1);
    if (lane == 0) { e00 = 1.f; e01 = 0.f; e10 = 0.f; e11 = 1.f; ec0 = 0.f; ec1 = 0.f; }

    // E = e o P
    const float E00 = e00 * P00 + e01 * P10;
    const float E01 = e00 * P01 + e01 * P11;
    const float E10 = e10 * P00 + e11 * P10;
    const float E11 = e10 * P01 + e11 * P11;
    const float Ec0 = e00 * Pc0 + e01 * Pc1 + ec0;
    const float Ec1 = e10 * Pc0 + e11 * Pc1 + ec1;

    // start state for this chunk: x_{t0-1} = E(x0)
    float xq0 = E00 * xa + E01 * xb + Ec0;
    float xq1 = E10 * xa + E11 * xb + Ec1;

    // ---- replay chunk from (S,o), emit outputs (Cd folded) ----
    float o0v[SPT], o1v[SPT];
#pragma unroll
    for (int s = 0; s < SPT; ++s) {
        o0v[s] = Cd00 * xq0 + Cd01 * xq1;
        o1v[s] = Cd10 * xq0 + Cd11 * xq1;
        const float nx0 = S00s[s] * xq0 + S01s[s] * xq1 + o0s[s];
        const float nx1 = S10s[s] * xq0 + S11s[s] * xq1 + o1s[s];
        xq0 = nx0; xq1 = nx1;
    }

    if (valid) {
        float* ob = out + (size_t)row * (TLEN * 2) + (size_t)r * 16;
        vfloat4 w0 = {o0v[0], o1v[0], o0v[1], o1v[1]};
        vfloat4 w1 = {o0v[2], o1v[2], o0v[3], o1v[3]};
        vfloat4 w2 = {o0v[4], o1v[4], o0v[5], o1v[5]};
        vfloat4 w3 = {o0v[6], o1v[6], o0v[7], o1v[7]};
        __builtin_nontemporal_store(w0, reinterpret_cast<vfloat4*>(ob));
        __builtin_nontemporal_store(w1, reinterpret_cast<vfloat4*>(ob) + 1);
        __builtin_nontemporal_store(w2, reinterpret_cast<vfloat4*>(ob) + 2);
        __builtin_nontemporal_store(w3, reinterpret_cast<vfloat4*>(ob) + 3);
    }
    if (r == 124) {  // owns steps 992..999 -> final state
        vfloat2 xf = {xq0, xq1};
        __builtin_nontemporal_store(
            xf, reinterpret_cast<vfloat2*>(out + (size_t)BATCH * (TLEN * 2) + 2 * row));
    }
}

extern "C" void kernel_launch(void* const* d_in, const int* in_sizes, int n_in,
                              void* d_out, int out_size, void* d_ws, size_t ws_size,
                              hipStream_t stream) {
    const float* xicovs = (const float*)d_in[0];
    const float* dyv    = (const float*)d_in[1];
    const float* cA     = (const float*)d_in[2];
    const float* Cm     = (const float*)d_in[3];
    const float* x0     = (const float*)d_in[4];
    const float* dtp    = (const float*)d_in[5];
    float* out = (float*)d_out;

    gd_scan_kernel<<<NBLK, TPB, 0, stream>>>(xicovs, dyv, cA, Cm, x0, dtp, out);
}

// Round 10
// 97.702 us; speedup vs baseline: 1.7796x; 1.7796x over previous
//
#include <hip/hip_runtime.h>

// GaussianDynamics recurrent cell as a parallel affine scan.
// x_t = S_t x_{t-1} + o_t,  S_t = I + (A - xic_t C) dt,  o_t = xic_t dy_t
// out_t = C x_{t-1} dt  (pre-update state)
//
// R10 = R7 structure (98.8us best: 1 row/block, global_load_lds staging,
// DPP scan, single barrier) + VALU cut via packed f32 (v_pk_fma_f32):
//  - All hot math in float2 ROW-PAIRS: S rows from xi scalars x nCd row-pairs,
//    M-update/scan-combine as scalar-x-pair pk_fma. Scan step 24 -> 14 ops.
//  - Tail guard hoisted: 1000/4=250 exactly -> thread-granular validity; one
//    identity overwrite after compose replaces 4x6 per-step cndmasks.
//  - R9 REVERTED: SPT=8 made stores/dy 64B-lane-stride scatter (WRITE_SIZE
//    148->222MB). Keep SPT=4: every global access 16B @ 16-32B lane stride.

constexpr int BATCH = 16384;
constexpr int TLEN  = 1000;
constexpr int TPB   = 256;
constexpr int SPT   = 4;     // TPB*SPT = 1024 >= TLEN; 1000/4=250 full chunks

typedef float vfloat4 __attribute__((ext_vector_type(4)));
typedef float vfloat2 __attribute__((ext_vector_type(2)));

template <int CTRL, int ROWMASK>
__device__ __forceinline__ float dppf(float oldv, float srcv) {
    return __int_as_float(__builtin_amdgcn_update_dpp(
        __float_as_int(oldv), __float_as_int(srcv), CTRL, ROWMASK, 0xf, false));
}

__global__ __launch_bounds__(TPB, 8) void gd_scan_kernel(
    const float* __restrict__ xicovs,  // [B,T,2,2]
    const float* __restrict__ dyv,     // [B,T,2]
    const float* __restrict__ cA,      // [2,2]
    const float* __restrict__ Cm,      // [2,2]
    const float* __restrict__ x0,      // [B,2]
    const float* __restrict__ dtp,     // [1]
    float* __restrict__ out)           // [B,T,2] then [B,2]
{
    __shared__ vfloat4 s_xc[1024];        // AoS granules (16B = one timestep)
    __shared__ float wsum[TPB / 64][6];

    const int b    = blockIdx.x;
    const int tid  = threadIdx.x;
    const int lane = tid & 63;
    const int wv   = tid >> 6;

    const int t0  = tid * SPT;
    const int t0m = (t0 <= TLEN - SPT) ? t0 : (TLEN - SPT);
    const bool valid = (t0 < TLEN);       // threads 250..255 idle (identity)

    const float* rowx = xicovs + (size_t)b * TLEN * 4;

    // ---- per-wave self-staging: 4x global_load_lds(16B) into own quarter,
    //      XOR-involution pre-swizzled source (G21) ----
#pragma unroll
    for (int k = 0; k < 4; ++k) {
        const int pw = k * 64 + lane;
        const int gw = pw ^ ((pw >> 3) & 7);
        int g = 256 * wv + gw;
        if (g > TLEN - 1) g = TLEN - 1;
        __builtin_amdgcn_global_load_lds(
            (const __attribute__((address_space(1))) void*)(rowx + (size_t)g * 4),
            (__attribute__((address_space(3))) void*)&s_xc[wv * 256 + k * 64],
            16, 0, 0);
    }

    // ---- dy: per-thread contiguous 32B (2x dwordx4), in flight with staging ----
    const vfloat4* gd4 = reinterpret_cast<const vfloat4*>(dyv + (size_t)b * TLEN * 2);
    const vfloat4 dA = gd4[(t0m >> 1)];
    const vfloat4 dB = gd4[(t0m >> 1) + 1];

    // ---- uniform params as row/col pairs ----
    const float dts = dtp[0];
    const vfloat2 CdColA = {Cm[0] * dts, Cm[2] * dts};   // (Cd00, Cd10)
    const vfloat2 CdColB = {Cm[1] * dts, Cm[3] * dts};   // (Cd01, Cd11)
    const vfloat2 nCdRow0 = {-Cm[0] * dts, -Cm[1] * dts};  // -(Cd00, Cd01)
    const vfloat2 nCdRow1 = {-Cm[2] * dts, -Cm[3] * dts};  // -(Cd10, Cd11)
    const vfloat2 AdRow0 = {1.f + cA[0] * dts, cA[1] * dts};
    const vfloat2 AdRow1 = {cA[2] * dts, 1.f + cA[3] * dts};
    const float xa = x0[2 * b], xb = x0[2 * b + 1];

    // ---- drain this wave's LDS-DMA (and dy) before reading LDS ----
    asm volatile("s_waitcnt vmcnt(0)" ::: "memory");

    // ---- read own 4 timesteps: swizzled ds_read_b128 ----
    vfloat4 xc[SPT];
#pragma unroll
    for (int s = 0; s < SPT; ++s) {
        const int gw  = 4 * lane + s;
        const int pos = gw ^ ((gw >> 3) & 7);
        xc[s] = s_xc[wv * 256 + pos];
    }
    const float dy0s[SPT] = {dA.x, dA.z, dB.x, dB.z};
    const float dy1s[SPT] = {dA.y, dA.w, dB.y, dB.w};

    // ---- per-step affine rows (Sa,Sb) + offset pair, compose in time order ----
    vfloat2 Sa[SPT], Sb[SPT], ov[SPT];
    vfloat2 mA = {1.f, 0.f}, mB = {0.f, 1.f}, cc = {0.f, 0.f};
#pragma unroll
    for (int s = 0; s < SPT; ++s) {
        const vfloat4 xi = xc[s];
        const vfloat2 sa = AdRow0 + xi.x * nCdRow0 + xi.y * nCdRow1;  // (S00,S01)
        const vfloat2 sb = AdRow1 + xi.z * nCdRow0 + xi.w * nCdRow1;  // (S10,S11)
        const float o0 = xi.x * dy0s[s] + xi.y * dy1s[s];
        const float o1 = xi.z * dy0s[s] + xi.w * dy1s[s];
        Sa[s] = sa; Sb[s] = sb; ov[s] = vfloat2{o0, o1};
        // M = S o M ; c = S c + o
        const vfloat2 nA = sa.x * mA + sa.y * mB;
        const vfloat2 nB = sb.x * mA + sb.y * mB;
        const float nc0 = sa.x * cc.x + sa.y * cc.y + o0;
        const float nc1 = sb.x * cc.x + sb.y * cc.y + o1;
        mA = nA; mB = nB; cc = vfloat2{nc0, nc1};
    }
    if (!valid) { mA = vfloat2{1.f, 0.f}; mB = vfloat2{0.f, 1.f}; cc = vfloat2{0.f, 0.f}; }

    // ---- wave-level inclusive scan via DPP + packed combine ----
#define SCAN_STEP(CTRL, RM)                                          \
    do {                                                             \
        vfloat2 smA, smB, scc;                                       \
        smA.x = dppf<CTRL, RM>(1.f, mA.x);                           \
        smA.y = dppf<CTRL, RM>(0.f, mA.y);                           \
        smB.x = dppf<CTRL, RM>(0.f, mB.x);                           \
        smB.y = dppf<CTRL, RM>(1.f, mB.y);                           \
        scc.x = dppf<CTRL, RM>(0.f, cc.x);                           \
        scc.y = dppf<CTRL, RM>(0.f, cc.y);                           \
        const vfloat2 nA = mA.x * smA + mA.y * smB;                  \
        const vfloat2 nB = mB.x * smA + mB.y * smB;                  \
        const float nc0 = mA.x * scc.x + mA.y * scc.y + cc.x;        \
        const float nc1 = mB.x * scc.x + mB.y * scc.y + cc.y;        \
        mA = nA; mB = nB; cc = vfloat2{nc0, nc1};                    \
    } while (0)

    SCAN_STEP(0x111, 0xf);  // row_shr:1
    SCAN_STEP(0x112, 0xf);  // row_shr:2
    SCAN_STEP(0x114, 0xf);  // row_shr:4
    SCAN_STEP(0x118, 0xf);  // row_shr:8
    SCAN_STEP(0x142, 0xa);  // row_bcast:15 -> rows 1,3
    SCAN_STEP(0x143, 0xc);  // row_bcast:31 -> rows 2,3
#undef SCAN_STEP

    // ---- inter-wave fixup ----
    if (lane == 63) {
        wsum[wv][0] = mA.x; wsum[wv][1] = mA.y;
        wsum[wv][2] = mB.x; wsum[wv][3] = mB.y;
        wsum[wv][4] = cc.x; wsum[wv][5] = cc.y;
    }
    __syncthreads();

    vfloat2 pA = {1.f, 0.f}, pB = {0.f, 1.f}, pc = {0.f, 0.f};
    for (int w = 0; w < wv; ++w) {
        const vfloat2 tA = {wsum[w][0], wsum[w][1]};
        const vfloat2 tB = {wsum[w][2], wsum[w][3]};
        const vfloat2 tc = {wsum[w][4], wsum[w][5]};
        const vfloat2 nA = tA.x * pA + tA.y * pB;   // P = T_w o P
        const vfloat2 nB = tB.x * pA + tB.y * pB;
        const float nc0 = tA.x * pc.x + tA.y * pc.y + tc.x;
        const float nc1 = tB.x * pc.x + tB.y * pc.y + tc.y;
        pA = nA; pB = nB; pc = vfloat2{nc0, nc1};
    }

    // ---- within-wave exclusive = inclusive of lane-1 ----
    vfloat2 eA, eB, ec;
    eA.x = __shfl_up(mA.x, 1); eA.y = __shfl_up(mA.y, 1);
    eB.x = __shfl_up(mB.x, 1); eB.y = __shfl_up(mB.y, 1);
    ec.x = __shfl_up(cc.x, 1); ec.y = __shfl_up(cc.y, 1);
    if (lane == 0) { eA = vfloat2{1.f, 0.f}; eB = vfloat2{0.f, 1.f}; ec = vfloat2{0.f, 0.f}; }

    // E = e o P
    const vfloat2 EA = eA.x * pA + eA.y * pB;
    const vfloat2 EB = eB.x * pA + eB.y * pB;
    const float Ec0 = eA.x * pc.x + eA.y * pc.y + ec.x;
    const float Ec1 = eB.x * pc.x + eB.y * pc.y + ec.y;

    // start state for this chunk: x_{t0-1} = E(x0)
    float xq0 = EA.x * xa + EA.y * xb + Ec0;
    float xq1 = EB.x * xa + EB.y * xb + Ec1;

    // ---- replay chunk, emit outputs (Cd folded; pair = (o0,o1) adjacent) ----
    vfloat2 op[SPT];
#pragma unroll
    for (int s = 0; s < SPT; ++s) {
        op[s] = xq0 * CdColA + xq1 * CdColB;
        const float nx0 = Sa[s].x * xq0 + Sa[s].y * xq1 + ov[s].x;
        const float nx1 = Sb[s].x * xq0 + Sb[s].y * xq1 + ov[s].y;
        xq0 = nx0; xq1 = nx1;
    }

    if (valid) {
        float* ob = out + (size_t)b * TLEN * 2 + (size_t)t0 * 2;
        vfloat4 w0 = {op[0].x, op[0].y, op[1].x, op[1].y};
        vfloat4 w1 = {op[2].x, op[2].y, op[3].x, op[3].y};
        __builtin_nontemporal_store(w0, reinterpret_cast<vfloat4*>(ob));
        __builtin_nontemporal_store(w1, reinterpret_cast<vfloat4*>(ob) + 1);
    }
    if (t0 == TLEN - SPT) {   // owns steps 996..999 -> final state
        vfloat2 xf = {xq0, xq1};
        __builtin_nontemporal_store(
            xf, reinterpret_cast<vfloat2*>(out + (size_t)BATCH * TLEN * 2 + 2 * b));
    }
}

extern "C" void kernel_launch(void* const* d_in, const int* in_sizes, int n_in,
                              void* d_out, int out_size, void* d_ws, size_t ws_size,
                              hipStream_t stream) {
    const float* xicovs = (const float*)d_in[0];
    const float* dyv    = (const float*)d_in[1];
    const float* cA     = (const float*)d_in[2];
    const float* Cm     = (const float*)d_in[3];
    const float* x0     = (const float*)d_in[4];
    const float* dtp    = (const float*)d_in[5];
    float* out = (float*)d_out;

    gd_scan_kernel<<<BATCH, TPB, 0, stream>>>(xicovs, dyv, cA, Cm, x0, dtp, out);
}